// Round 3
// baseline (123.535 us; speedup 1.0000x reference)
//
#include <hip/hip_runtime.h>

#define B_    16
#define L_    1024
#define H_    8
#define QSCALE 0.25510940349191965f              // (1/sqrt(32)) * log2(e)  (exp -> exp2)

typedef __attribute__((ext_vector_type(8))) short bf16x8;
typedef __attribute__((ext_vector_type(4))) float f32x4;
typedef __attribute__((ext_vector_type(16))) float f32x16;
typedef unsigned short u16t;

__device__ inline u16t f2bf(float f) {
    unsigned u = __float_as_uint(f);
    u = (u + 0x7FFF + ((u >> 16) & 1)) >> 16;
    return (u16t)u;
}
__device__ inline unsigned f2bf_pk(float a, float b) {
    unsigned ua = __float_as_uint(a);
    unsigned ub = __float_as_uint(b);
    ua = (ua + 0x7FFF + ((ua >> 16) & 1)) >> 16;
    ub = (ub + 0x7FFF + ((ub >> 16) & 1)) >> 16;
    return ua | (ub << 16);
}
__device__ inline uint2 f2bf_pk4(float a, float b, float c, float d) {
    uint2 u; u.x = f2bf_pk(a, b); u.y = f2bf_pk(c, d); return u;
}
// truncating bf16 pack: low16 = hi(f0), high16 = hi(f1) — one v_perm_b32
__device__ inline unsigned trunc_pk(float f0, float f1) {
    return __builtin_amdgcn_perm(__float_as_uint(f1), __float_as_uint(f0), 0x07060302u);
}
// async global->LDS DMA, 16B per lane (global_load_lds_dwordx4)
__device__ inline void async16(const u16t* g, u16t* l) {
    __builtin_amdgcn_global_load_lds(
        (const __attribute__((address_space(1))) unsigned int*)g,
        (__attribute__((address_space(3))) unsigned int*)l, 16, 0, 0);
}
// v_permlane32_swap_b32: after call a = [a(0:31), b(0:31)], b = [a(32:63), b(32:63)]
typedef __attribute__((ext_vector_type(2))) unsigned uint2v;
__device__ inline void permswap32(unsigned &a, unsigned &b) {
    uint2v r = __builtin_amdgcn_permlane32_swap(a, b, false, false);
    a = r.x; b = r.y;
}

// ---------------------------------------------------------------------------
// Fused pre-pass (R12): one kernel replaces wprep + prep (saves a launch).
//   blocks [0,144):  fp32 weights -> bf16 images in exact padded LDS layouts
//   blocks [144,400): x (B,128,1024) fp32 -> xbT (B,1024,128) bf16 transpose
// ---------------------------------------------------------------------------
__global__ __launch_bounds__(256) void pre_kernel(
    const float* __restrict__ w_qkv, const float* __restrict__ w_o,
    const float* __restrict__ w_res, const float* __restrict__ x,
    u16t* __restrict__ wqkvF, u16t* __restrict__ woF, u16t* __restrict__ wrF,
    u16t* __restrict__ xbT)
{
    const int bid = blockIdx.x, tid = threadIdx.x;
    if (bid < 144) {
        if (bid < 96) {                    // w_qkv: 8 h x 12288 elems (12 blocks/h)
            const int h = bid / 12, rb = bid - h * 12;
            const int e = rb * 1024 + tid * 4;
            const int row = e >> 7, c = e & 127;
            const float4 w = *(const float4*)(w_qkv + (long)h * 12288 + e);
            *(uint2*)(wqkvF + (long)h * 14336 + row * 136 + c) = f2bf_pk4(w.x, w.y, w.z, w.w);
        } else if (bid < 128) {            // w_o: 2 oblk x 16384 elems
            const int g = (bid - 96) * 1024 + tid * 4;
            const int oblk = g >> 14, rem = g & 16383;
            const int row = rem >> 8, c = rem & 255;
            const float4 w = *(const float4*)(w_o + g);
            *(uint2*)(woF + (long)oblk * 16896 + row * 264 + c) = f2bf_pk4(w.x, w.y, w.z, w.w);
        } else {                           // w_res: 2 oblk x 8192 elems
            const int g = (bid - 128) * 1024 + tid * 4;
            const int oblk = g >> 13, rem = g & 8191;
            const int row = rem >> 7, c = rem & 127;
            const float4 w = *(const float4*)(w_res + g);
            *(uint2*)(wrF + (long)oblk * 8704 + row * 136 + c) = f2bf_pk4(w.x, w.y, w.z, w.w);
        }
        return;
    }
    // x transpose branch
    __shared__ u16t T[64][144];
    const int bid2 = bid - 144;
    const int b = bid2 >> 4, l0 = (bid2 & 15) * 64;
#pragma unroll
    for (int i = 0; i < 8; i++) {
        const int c = i * 16 + (tid >> 4);
        const int l = (tid & 15) * 4;
        const float4 v = *(const float4*)(x + ((long)b * 128 + c) * 1024 + l0 + l);
        T[l + 0][c] = f2bf(v.x);
        T[l + 1][c] = f2bf(v.y);
        T[l + 2][c] = f2bf(v.z);
        T[l + 3][c] = f2bf(v.w);
    }
    __syncthreads();
#pragma unroll
    for (int i = 0; i < 4; i++) {
        const int l  = i * 16 + (tid >> 4);
        const int c0 = (tid & 15) * 8;
        *(uint4*)(xbT + ((long)b * 1024 + l0 + l) * 128 + c0) = *(const uint4*)&T[l][c0];
    }
}

// ---------------------------------------------------------------------------
// QKV GEMM (unchanged from R11): DMA-staged bf16 weights, 48 MFMAs,
// epilogue -> qT (QSCALE folded) / kF (32x32 frag image) / vF.
// ---------------------------------------------------------------------------
__global__ __launch_bounds__(256) void qkv_gemm_kernel(
    const u16t* __restrict__ wqkvF, const u16t* __restrict__ xbT,
    const float* __restrict__ b_qkv,
    u16t* __restrict__ qT, u16t* __restrict__ kF, u16t* __restrict__ vF)
{
    __shared__ __align__(16) u16t Ws[14336];      // [96][136] + DMA pad

    const int lblk = blockIdx.x * 128;
    const int bh = blockIdx.y;
    const int b = bh >> 3, h = bh & 7;
    const int tid = threadIdx.x, lane = tid & 63, wv = tid >> 6;
    const int l15 = lane & 15, quad = lane >> 4;
    const int lw = lblk + wv * 32;

    // stage weights: pure DMA, 7 x (256 lanes x 16 B)
    {
        const u16t* wsrc = wqkvF + (long)h * 14336;
#pragma unroll
        for (int it = 0; it < 7; it++)
            async16(wsrc + it * 2048 + tid * 8, Ws + it * 2048 + tid * 8);
    }

    // preload all x fragments (8 x b128, no reuse-rotation)
    bf16x8 bfr[4][2];
    {
        const u16t* xr0 = xbT + ((long)b * 1024 + lw + l15) * 128 + quad * 8;
        const u16t* xr1 = xr0 + 16 * 128;
#pragma unroll
        for (int ks = 0; ks < 4; ks++) {
            bfr[ks][0] = *(const bf16x8*)(xr0 + ks * 32);
            bfr[ks][1] = *(const bf16x8*)(xr1 + ks * 32);
        }
    }
    __syncthreads();                              // drains DMA (vmcnt 0)

    f32x4 acc[6][2];
#pragma unroll
    for (int mi = 0; mi < 6; mi++)
#pragma unroll
        for (int ni = 0; ni < 2; ni++) acc[mi][ni] = (f32x4)0.f;

#pragma unroll
    for (int ks = 0; ks < 4; ks++) {
#pragma unroll
        for (int mi = 0; mi < 6; mi++) {
            const bf16x8 af = *(const bf16x8*)&Ws[(mi * 16 + l15) * 136 + ks * 32 + quad * 8];
            acc[mi][0] = __builtin_amdgcn_mfma_f32_16x16x32_bf16(af, bfr[ks][0], acc[mi][0], 0, 0, 0);
            acc[mi][1] = __builtin_amdgcn_mfma_f32_16x16x32_bf16(af, bfr[ks][1], acc[mi][1], 0, 0, 0);
        }
    }

    const long bh_ = bh;
#pragma unroll
    for (int mi = 0; mi < 6; mi++) {
        const float4 bv = *(const float4*)(b_qkv + h * 96 + mi * 16 + quad * 4);
        const float* bias = (const float*)&bv;
#pragma unroll
        for (int ni = 0; ni < 2; ni++) {
            const int l = lw + ni * 16 + l15;
            const f32x4 a = acc[mi][ni];
            if (mi < 2) {           // Q: fold QSCALE, transposed [s][d]
                const uint2 u = f2bf_pk4((a[0] + bias[0]) * QSCALE, (a[1] + bias[1]) * QSCALE,
                                         (a[2] + bias[2]) * QSCALE, (a[3] + bias[3]) * QSCALE);
                *(uint2*)(qT + (bh_ * 1024 + l) * 32 + mi * 16 + quad * 4) = u;
            } else if (mi < 4) {    // K -> kF [c][ttile][khalf][hi][t5][8j]
                const int t = l, c = t >> 6, tl = t & 63;
                const uint2 u = f2bf_pk4(a[0] + bias[0], a[1] + bias[1],
                                         a[2] + bias[2], a[3] + bias[3]);
                *(uint2*)(kF + (bh_ * 16 + c) * 2048 + (tl >> 5) * 1024 + (mi - 2) * 512
                          + (quad >> 1) * 256 + (tl & 31) * 8 + (quad & 1) * 4) = u;
            } else {                // V -> vF [c][t_in>>3][d][8j]
                const int t = l, c = t >> 6, tq = (t >> 3) & 7, j = t & 7;
                u16t* vb = vF + (bh_ * 16 + c) * 2048 + tq * 256 + j;
#pragma unroll
                for (int r = 0; r < 4; r++)
                    vb[((mi - 4) * 16 + quad * 4 + r) * 8] = f2bf(a[r] + bias[r]);
            }
        }
    }
}

// ---------------------------------------------------------------------------
// Attention R12: 8 rounds x 128 t (was 16 x 64 t) — halves the serial
// barrier+vmcnt-drain count and doubles compute per DMA front.  Per round:
// 16 KB K + 16 KB V staged (2 shots each half-block); 4 x 32-t tiles of
// {2 QK MFMA, 16 exp2, pack+permswap, 2 PV MFMA}.  Same math order as R11.
// ---------------------------------------------------------------------------
__global__ __launch_bounds__(512) void attn_kernel12(
    const u16t* __restrict__ qT, const u16t* __restrict__ kF,
    const u16t* __restrict__ vF, u16t* __restrict__ zT)
{
    __shared__ __align__(16) u16t Ks[2][4096];
    __shared__ __align__(16) u16t Vs[2][4096];

    const int bh = blockIdx.x;
    const int b = bh >> 3, h = bh & 7;
    const int sblk = blockIdx.y * 256;
    const int tid = threadIdx.x, lane = tid & 63, wv = tid >> 6;
    const int l31 = lane & 31, hi = lane >> 5;

    const int sw = sblk + wv * 32;
    bf16x8 qf[2];
    qf[0] = *(const bf16x8*)(qT + ((long)bh * 1024 + sw + l31) * 32 + hi * 8);
    qf[1] = *(const bf16x8*)(qT + ((long)bh * 1024 + sw + l31) * 32 + 16 + hi * 8);

    const u16t* kg = kF + (long)bh * 32768;
    const u16t* vg = vF + (long)bh * 32768;

    // prime round 0: 8 KB K (waves 0-3) + 8 KB V (waves 4-7), 2 shots each
    if (tid < 256) {
        async16(kg + tid * 8, &Ks[0][tid * 8]);
        async16(kg + 2048 + tid * 8, &Ks[0][2048 + tid * 8]);
    } else {
        const int t2 = tid - 256;
        async16(vg + t2 * 8, &Vs[0][t2 * 8]);
        async16(vg + 2048 + t2 * 8, &Vs[0][2048 + t2 * 8]);
    }

    f32x16 zacc = (f32x16)0.f;           // z[d=(r&3)+8*(r>>2)+4*hi][s=lane&31]
    f32x4 lacc = (f32x4)0.f;

    for (int r = 0; r < 8; ++r) {
        const int buf = r & 1;
        __syncthreads();                 // buf[r] DMA drained; prev compute done
        if (r < 7) {
            const int o = (r + 1) * 4096;
            if (tid < 256) {
                async16(kg + o + tid * 8, &Ks[buf ^ 1][tid * 8]);
                async16(kg + o + 2048 + tid * 8, &Ks[buf ^ 1][2048 + tid * 8]);
            } else {
                const int t2 = tid - 256;
                async16(vg + o + t2 * 8, &Vs[buf ^ 1][t2 * 8]);
                async16(vg + o + 2048 + t2 * 8, &Vs[buf ^ 1][2048 + t2 * 8]);
            }
        }

#pragma unroll
        for (int tl = 0; tl < 4; tl++) {
            const bf16x8 k0 = *(const bf16x8*)&Ks[buf][tl * 1024 + lane * 8];
            const bf16x8 k1 = *(const bf16x8*)&Ks[buf][tl * 1024 + 512 + lane * 8];
            f32x16 sv = __builtin_amdgcn_mfma_f32_32x32x16_bf16(k0, qf[0], (f32x16)0.f, 0, 0, 0);
            sv = __builtin_amdgcn_mfma_f32_32x32x16_bf16(k1, qf[1], sv, 0, 0, 0);

            f32x16 ev;
#pragma unroll
            for (int i = 0; i < 16; i++) ev[i] = __builtin_amdgcn_exp2f(sv[i]);
#pragma unroll
            for (int i = 0; i < 16; i++) lacc[i & 3] += ev[i];

            unsigned d0 = trunc_pk(ev[0], ev[1]),   d2 = trunc_pk(ev[4], ev[5]);
            unsigned d1 = trunc_pk(ev[2], ev[3]),   d3 = trunc_pk(ev[6], ev[7]);
            permswap32(d0, d2);
            permswap32(d1, d3);
            union { bf16x8 v; unsigned u[4]; } p0;
            p0.u[0] = d0; p0.u[1] = d1; p0.u[2] = d2; p0.u[3] = d3;
            unsigned e0 = trunc_pk(ev[8], ev[9]),   e2 = trunc_pk(ev[12], ev[13]);
            unsigned e1 = trunc_pk(ev[10], ev[11]), e3 = trunc_pk(ev[14], ev[15]);
            permswap32(e0, e2);
            permswap32(e1, e3);
            union { bf16x8 v; unsigned u[4]; } p1;
            p1.u[0] = e0; p1.u[1] = e1; p1.u[2] = e2; p1.u[3] = e3;

            const bf16x8 vf0 = *(const bf16x8*)&Vs[buf][(tl * 2 + 0) * 512 + lane * 8];
            const bf16x8 vf1 = *(const bf16x8*)&Vs[buf][(tl * 2 + 1) * 512 + lane * 8];
            zacc = __builtin_amdgcn_mfma_f32_32x32x16_bf16(vf0, p0.v, zacc, 0, 0, 0);
            zacc = __builtin_amdgcn_mfma_f32_32x32x16_bf16(vf1, p1.v, zacc, 0, 0, 0);
        }
    }

    float lf = (lacc[0] + lacc[1]) + (lacc[2] + lacc[3]);
    lf += __shfl_xor(lf, 32);
    const float rl = 1.f / lf;
    const int s = sblk + wv * 32 + l31;
    u16t* zrow = zT + ((long)b * 1024 + s) * 256 + h * 32;
#pragma unroll
    for (int g = 0; g < 4; g++) {
        const uint2 u = f2bf_pk4(zacc[g * 4 + 0] * rl, zacc[g * 4 + 1] * rl,
                                 zacc[g * 4 + 2] * rl, zacc[g * 4 + 3] * rl);
        *(uint2*)(zrow + g * 8 + hi * 4) = u;
    }
}

// ---------------------------------------------------------------------------
// Fused output GEMM (unchanged from R11): pure-DMA weight staging, 24 MFMAs.
// ---------------------------------------------------------------------------
__global__ __launch_bounds__(256) void out_gemm_kernel(
    const u16t* __restrict__ woF, const u16t* __restrict__ wrF,
    const u16t* __restrict__ zT, const u16t* __restrict__ xbT,
    const float* __restrict__ b_o, const float* __restrict__ b_res,
    float* __restrict__ out)
{
    __shared__ __align__(16) u16t Wo[16896];   // [64][264]
    __shared__ __align__(16) u16t Wr[8704];    // [64][136]

    const int lblk = blockIdx.x * 32, oblk = blockIdx.y, b = blockIdx.z;
    const int tid = threadIdx.x, lane = tid & 63, wv = tid >> 6;
    const int wm = wv >> 1, wn = wv & 1;
    const int l15 = lane & 15, quad = lane >> 4;
    const int ow = oblk * 64 + wm * 32;
    const int lw = lblk + wn * 16;

    // stage weights: pure DMA
    {
        const u16t* wo_src = woF + (long)oblk * 16896;
#pragma unroll
        for (int it = 0; it < 8; it++)
            async16(wo_src + it * 2048 + tid * 8, Wo + it * 2048 + tid * 8);
        if (tid < 64) async16(wo_src + 16384 + tid * 8, Wo + 16384 + tid * 8);
        const u16t* wr_src = wrF + (long)oblk * 8704;
#pragma unroll
        for (int it = 0; it < 4; it++)
            async16(wr_src + it * 2048 + tid * 8, Wr + it * 2048 + tid * 8);
        if (tid < 64) async16(wr_src + 8192 + tid * 8, Wr + 8192 + tid * 8);
    }

    // preload all 12 B fragments
    bf16x8 bfz[8], bfx[4];
    {
        const u16t* zrow = zT + ((long)b * 1024 + lw + l15) * 256 + quad * 8;
        const u16t* xrow = xbT + ((long)b * 1024 + lw + l15) * 128 + quad * 8;
#pragma unroll
        for (int ks = 0; ks < 8; ks++) bfz[ks] = *(const bf16x8*)(zrow + ks * 32);
#pragma unroll
        for (int ks = 0; ks < 4; ks++) bfx[ks] = *(const bf16x8*)(xrow + ks * 32);
    }
    __syncthreads();                           // drains DMA

    f32x4 acc0 = (f32x4)0.f, acc1 = (f32x4)0.f;

#pragma unroll
    for (int ks = 0; ks < 8; ks++) {
        const bf16x8 af0 = *(const bf16x8*)&Wo[(wm * 32 + l15) * 264 + ks * 32 + quad * 8];
        const bf16x8 af1 = *(const bf16x8*)&Wo[(wm * 32 + 16 + l15) * 264 + ks * 32 + quad * 8];
        acc0 = __builtin_amdgcn_mfma_f32_16x16x32_bf16(af0, bfz[ks], acc0, 0, 0, 0);
        acc1 = __builtin_amdgcn_mfma_f32_16x16x32_bf16(af1, bfz[ks], acc1, 0, 0, 0);
    }
#pragma unroll
    for (int ks = 0; ks < 4; ks++) {
        const bf16x8 af0 = *(const bf16x8*)&Wr[(wm * 32 + l15) * 136 + ks * 32 + quad * 8];
        const bf16x8 af1 = *(const bf16x8*)&Wr[(wm * 32 + 16 + l15) * 136 + ks * 32 + quad * 8];
        acc0 = __builtin_amdgcn_mfma_f32_16x16x32_bf16(af0, bfx[ks], acc0, 0, 0, 0);
        acc1 = __builtin_amdgcn_mfma_f32_16x16x32_bf16(af1, bfx[ks], acc1, 0, 0, 0);
    }

    const int lcol = lw + l15;
#pragma unroll
    for (int mi = 0; mi < 2; mi++) {
        const f32x4 a = (mi == 0) ? acc0 : acc1;
        const float4 bo = *(const float4*)(b_o + ow + mi * 16 + quad * 4);
        const float4 br = *(const float4*)(b_res + ow + mi * 16 + quad * 4);
        const float* bop = (const float*)&bo;
        const float* brp = (const float*)&br;
#pragma unroll
        for (int r = 0; r < 4; r++) {
            const int o = ow + mi * 16 + quad * 4 + r;
            out[((long)b * 128 + o) * 1024 + lcol] = a[r] + bop[r] + brp[r];
        }
    }
}

// ---------------------------------------------------------------------------
extern "C" void kernel_launch(void* const* d_in, const int* in_sizes, int n_in,
                              void* d_out, int out_size, void* d_ws, size_t ws_size,
                              hipStream_t stream)
{
    const float* x     = (const float*)d_in[0];
    const float* w_qkv = (const float*)d_in[1];
    const float* b_qkv = (const float*)d_in[2];
    const float* w_o   = (const float*)d_in[3];
    const float* b_o   = (const float*)d_in[4];
    const float* w_res = (const float*)d_in[5];
    const float* b_res = (const float*)d_in[6];
    float* out = (float*)d_out;

    u16t* xbT = (u16t*)d_ws;                   // [B][1024][128]
    u16t* qT  = xbT + (size_t)2097152;         // [B][H][1024][32]
    u16t* kF  = qT  + (size_t)4194304;         // [B*H][16 chunks][2048] (32x32 frag image)
    u16t* vF  = kF  + (size_t)4194304;         // [B*H][16 chunks][2048]
    u16t* zT  = vF  + (size_t)4194304;         // [B][1024][256]
    u16t* wqkvF = zT + (size_t)4194304;        // 8 x 14336
    u16t* woF   = wqkvF + (size_t)114688;      // 2 x 16896
    u16t* wrF   = woF + (size_t)33792;         // 2 x 8704

    pre_kernel<<<dim3(400), 256, 0, stream>>>(w_qkv, w_o, w_res, x, wqkvF, woF, wrF, xbT);
    qkv_gemm_kernel<<<dim3(8, 128), 256, 0, stream>>>(wqkvF, xbT, b_qkv, qT, kF, vF);
    attn_kernel12<<<dim3(128, 4), 512, 0, stream>>>(qT, kF, vF, zT);
    out_gemm_kernel<<<dim3(32, 2, 16), 256, 0, stream>>>(woF, wrF, zT, xbT, b_o, b_res, out);
}

// Round 4
// 120.857 us; speedup vs baseline: 1.0222x; 1.0222x over previous
//
#include <hip/hip_runtime.h>

#define B_    16
#define L_    1024
#define H_    8
#define QSCALE 0.25510940349191965f              // (1/sqrt(32)) * log2(e)  (exp -> exp2)

typedef __attribute__((ext_vector_type(8))) short bf16x8;
typedef __attribute__((ext_vector_type(4))) float f32x4;
typedef __attribute__((ext_vector_type(16))) float f32x16;
typedef unsigned short u16t;

__device__ inline u16t f2bf(float f) {
    unsigned u = __float_as_uint(f);
    u = (u + 0x7FFF + ((u >> 16) & 1)) >> 16;
    return (u16t)u;
}
__device__ inline unsigned f2bf_pk(float a, float b) {
    unsigned ua = __float_as_uint(a);
    unsigned ub = __float_as_uint(b);
    ua = (ua + 0x7FFF + ((ua >> 16) & 1)) >> 16;
    ub = (ub + 0x7FFF + ((ub >> 16) & 1)) >> 16;
    return ua | (ub << 16);
}
__device__ inline uint2 f2bf_pk4(float a, float b, float c, float d) {
    uint2 u; u.x = f2bf_pk(a, b); u.y = f2bf_pk(c, d); return u;
}
// truncating bf16 pack: low16 = hi(f0), high16 = hi(f1) — one v_perm_b32
__device__ inline unsigned trunc_pk(float f0, float f1) {
    return __builtin_amdgcn_perm(__float_as_uint(f1), __float_as_uint(f0), 0x07060302u);
}
// async global->LDS DMA, 16B per lane (global_load_lds_dwordx4)
__device__ inline void async16(const u16t* g, u16t* l) {
    __builtin_amdgcn_global_load_lds(
        (const __attribute__((address_space(1))) unsigned int*)g,
        (__attribute__((address_space(3))) unsigned int*)l, 16, 0, 0);
}
// v_permlane32_swap_b32: after call a = [a(0:31), b(0:31)], b = [a(32:63), b(32:63)]
typedef __attribute__((ext_vector_type(2))) unsigned uint2v;
__device__ inline void permswap32(unsigned &a, unsigned &b) {
    uint2v r = __builtin_amdgcn_permlane32_swap(a, b, false, false);
    a = r.x; b = r.y;
}

// ---------------------------------------------------------------------------
// Fused pre-pass (kept from R12): one kernel replaces wprep + prep.
//   blocks [0,144):  fp32 weights -> bf16 images in exact padded LDS layouts
//   blocks [144,400): x (B,128,1024) fp32 -> xbT (B,1024,128) bf16 transpose
// ---------------------------------------------------------------------------
__global__ __launch_bounds__(256) void pre_kernel(
    const float* __restrict__ w_qkv, const float* __restrict__ w_o,
    const float* __restrict__ w_res, const float* __restrict__ x,
    u16t* __restrict__ wqkvF, u16t* __restrict__ woF, u16t* __restrict__ wrF,
    u16t* __restrict__ xbT)
{
    const int bid = blockIdx.x, tid = threadIdx.x;
    if (bid < 144) {
        if (bid < 96) {                    // w_qkv: 8 h x 12288 elems (12 blocks/h)
            const int h = bid / 12, rb = bid - h * 12;
            const int e = rb * 1024 + tid * 4;
            const int row = e >> 7, c = e & 127;
            const float4 w = *(const float4*)(w_qkv + (long)h * 12288 + e);
            *(uint2*)(wqkvF + (long)h * 14336 + row * 136 + c) = f2bf_pk4(w.x, w.y, w.z, w.w);
        } else if (bid < 128) {            // w_o: 2 oblk x 16384 elems
            const int g = (bid - 96) * 1024 + tid * 4;
            const int oblk = g >> 14, rem = g & 16383;
            const int row = rem >> 8, c = rem & 255;
            const float4 w = *(const float4*)(w_o + g);
            *(uint2*)(woF + (long)oblk * 16896 + row * 264 + c) = f2bf_pk4(w.x, w.y, w.z, w.w);
        } else {                           // w_res: 2 oblk x 8192 elems
            const int g = (bid - 128) * 1024 + tid * 4;
            const int oblk = g >> 13, rem = g & 8191;
            const int row = rem >> 7, c = rem & 127;
            const float4 w = *(const float4*)(w_res + g);
            *(uint2*)(wrF + (long)oblk * 8704 + row * 136 + c) = f2bf_pk4(w.x, w.y, w.z, w.w);
        }
        return;
    }
    // x transpose branch
    __shared__ u16t T[64][144];
    const int bid2 = bid - 144;
    const int b = bid2 >> 4, l0 = (bid2 & 15) * 64;
#pragma unroll
    for (int i = 0; i < 8; i++) {
        const int c = i * 16 + (tid >> 4);
        const int l = (tid & 15) * 4;
        const float4 v = *(const float4*)(x + ((long)b * 128 + c) * 1024 + l0 + l);
        T[l + 0][c] = f2bf(v.x);
        T[l + 1][c] = f2bf(v.y);
        T[l + 2][c] = f2bf(v.z);
        T[l + 3][c] = f2bf(v.w);
    }
    __syncthreads();
#pragma unroll
    for (int i = 0; i < 4; i++) {
        const int l  = i * 16 + (tid >> 4);
        const int c0 = (tid & 15) * 8;
        *(uint4*)(xbT + ((long)b * 1024 + l0 + l) * 128 + c0) = *(const uint4*)&T[l][c0];
    }
}

// ---------------------------------------------------------------------------
// QKV GEMM (unchanged from R11): DMA-staged bf16 weights, 48 MFMAs,
// epilogue -> qT (QSCALE folded) / kF (32x32 frag image) / vF.
// ---------------------------------------------------------------------------
__global__ __launch_bounds__(256) void qkv_gemm_kernel(
    const u16t* __restrict__ wqkvF, const u16t* __restrict__ xbT,
    const float* __restrict__ b_qkv,
    u16t* __restrict__ qT, u16t* __restrict__ kF, u16t* __restrict__ vF)
{
    __shared__ __align__(16) u16t Ws[14336];      // [96][136] + DMA pad

    const int lblk = blockIdx.x * 128;
    const int bh = blockIdx.y;
    const int b = bh >> 3, h = bh & 7;
    const int tid = threadIdx.x, lane = tid & 63, wv = tid >> 6;
    const int l15 = lane & 15, quad = lane >> 4;
    const int lw = lblk + wv * 32;

    // stage weights: pure DMA, 7 x (256 lanes x 16 B)
    {
        const u16t* wsrc = wqkvF + (long)h * 14336;
#pragma unroll
        for (int it = 0; it < 7; it++)
            async16(wsrc + it * 2048 + tid * 8, Ws + it * 2048 + tid * 8);
    }

    // preload all x fragments (8 x b128, no reuse-rotation)
    bf16x8 bfr[4][2];
    {
        const u16t* xr0 = xbT + ((long)b * 1024 + lw + l15) * 128 + quad * 8;
        const u16t* xr1 = xr0 + 16 * 128;
#pragma unroll
        for (int ks = 0; ks < 4; ks++) {
            bfr[ks][0] = *(const bf16x8*)(xr0 + ks * 32);
            bfr[ks][1] = *(const bf16x8*)(xr1 + ks * 32);
        }
    }
    __syncthreads();                              // drains DMA (vmcnt 0)

    f32x4 acc[6][2];
#pragma unroll
    for (int mi = 0; mi < 6; mi++)
#pragma unroll
        for (int ni = 0; ni < 2; ni++) acc[mi][ni] = (f32x4)0.f;

#pragma unroll
    for (int ks = 0; ks < 4; ks++) {
#pragma unroll
        for (int mi = 0; mi < 6; mi++) {
            const bf16x8 af = *(const bf16x8*)&Ws[(mi * 16 + l15) * 136 + ks * 32 + quad * 8];
            acc[mi][0] = __builtin_amdgcn_mfma_f32_16x16x32_bf16(af, bfr[ks][0], acc[mi][0], 0, 0, 0);
            acc[mi][1] = __builtin_amdgcn_mfma_f32_16x16x32_bf16(af, bfr[ks][1], acc[mi][1], 0, 0, 0);
        }
    }

    const long bh_ = bh;
#pragma unroll
    for (int mi = 0; mi < 6; mi++) {
        const float4 bv = *(const float4*)(b_qkv + h * 96 + mi * 16 + quad * 4);
        const float* bias = (const float*)&bv;
#pragma unroll
        for (int ni = 0; ni < 2; ni++) {
            const int l = lw + ni * 16 + l15;
            const f32x4 a = acc[mi][ni];
            if (mi < 2) {           // Q: fold QSCALE, transposed [s][d]
                const uint2 u = f2bf_pk4((a[0] + bias[0]) * QSCALE, (a[1] + bias[1]) * QSCALE,
                                         (a[2] + bias[2]) * QSCALE, (a[3] + bias[3]) * QSCALE);
                *(uint2*)(qT + (bh_ * 1024 + l) * 32 + mi * 16 + quad * 4) = u;
            } else if (mi < 4) {    // K -> kF [c][ttile][khalf][hi][t5][8j]
                const int t = l, c = t >> 6, tl = t & 63;
                const uint2 u = f2bf_pk4(a[0] + bias[0], a[1] + bias[1],
                                         a[2] + bias[2], a[3] + bias[3]);
                *(uint2*)(kF + (bh_ * 16 + c) * 2048 + (tl >> 5) * 1024 + (mi - 2) * 512
                          + (quad >> 1) * 256 + (tl & 31) * 8 + (quad & 1) * 4) = u;
            } else {                // V -> vF [c][t_in>>3][d][8j]
                const int t = l, c = t >> 6, tq = (t >> 3) & 7, j = t & 7;
                u16t* vb = vF + (bh_ * 16 + c) * 2048 + tq * 256 + j;
#pragma unroll
                for (int r = 0; r < 4; r++)
                    vb[((mi - 4) * 16 + quad * 4 + r) * 8] = f2bf(a[r] + bias[r]);
            }
        }
    }
}

// ---------------------------------------------------------------------------
// Attention R13: reverted to R11's measured-best 16 rounds x 64 t structure
// (4 KB K + 4 KB V per round, one async16 per thread), plus s_setprio(1)
// around the per-tile MFMA/exp2 compute cluster (T5: helps when DMA-issuing
// and compute waves coexist on the CU).
// ---------------------------------------------------------------------------
__global__ __launch_bounds__(512) void attn_kernel13(
    const u16t* __restrict__ qT, const u16t* __restrict__ kF,
    const u16t* __restrict__ vF, u16t* __restrict__ zT)
{
    __shared__ __align__(16) u16t Ks[2][2048];
    __shared__ __align__(16) u16t Vs[2][2048];

    const int bh = blockIdx.x;
    const int b = bh >> 3, h = bh & 7;
    const int sblk = blockIdx.y * 256;
    const int tid = threadIdx.x, lane = tid & 63, wv = tid >> 6;
    const int l31 = lane & 31, hi = lane >> 5;

    const int sw = sblk + wv * 32;
    bf16x8 qf[2];
    qf[0] = *(const bf16x8*)(qT + ((long)bh * 1024 + sw + l31) * 32 + hi * 8);
    qf[1] = *(const bf16x8*)(qT + ((long)bh * 1024 + sw + l31) * 32 + 16 + hi * 8);

    const u16t* kg = kF + (long)bh * 32768;
    const u16t* vg = vF + (long)bh * 32768;

    if (tid < 256) async16(kg + tid * 8, &Ks[0][tid * 8]);
    else           async16(vg + (tid - 256) * 8, &Vs[0][(tid - 256) * 8]);

    f32x16 zacc = (f32x16)0.f;           // z[d=(r&3)+8*(r>>2)+4*hi][s=lane&31]
    f32x4 lacc = (f32x4)0.f;

    for (int c = 0; c < 16; ++c) {
        const int buf = c & 1;
        __syncthreads();                 // buf[c] DMA drained; prev compute done
        if (c < 15) {
            const int o = (c + 1) * 2048;
            if (tid < 256) async16(kg + o + tid * 8, &Ks[buf ^ 1][tid * 8]);
            else           async16(vg + o + (tid - 256) * 8, &Vs[buf ^ 1][(tid - 256) * 8]);
        }

        bf16x8 vf[4];
#pragma unroll
        for (int i = 0; i < 4; i++) vf[i] = *(const bf16x8*)&Vs[buf][i * 512 + lane * 8];

        __builtin_amdgcn_s_setprio(1);
#pragma unroll
        for (int tt = 0; tt < 2; tt++) {
            const bf16x8 k0 = *(const bf16x8*)&Ks[buf][(tt * 2 + 0) * 512 + lane * 8];
            const bf16x8 k1 = *(const bf16x8*)&Ks[buf][(tt * 2 + 1) * 512 + lane * 8];
            f32x16 sv = __builtin_amdgcn_mfma_f32_32x32x16_bf16(k0, qf[0], (f32x16)0.f, 0, 0, 0);
            sv = __builtin_amdgcn_mfma_f32_32x32x16_bf16(k1, qf[1], sv, 0, 0, 0);

            f32x16 ev;
#pragma unroll
            for (int i = 0; i < 16; i++) ev[i] = __builtin_amdgcn_exp2f(sv[i]);
#pragma unroll
            for (int i = 0; i < 16; i++) lacc[i & 3] += ev[i];

            unsigned d0 = trunc_pk(ev[0], ev[1]),   d2 = trunc_pk(ev[4], ev[5]);
            unsigned d1 = trunc_pk(ev[2], ev[3]),   d3 = trunc_pk(ev[6], ev[7]);
            permswap32(d0, d2);
            permswap32(d1, d3);
            union { bf16x8 v; unsigned u[4]; } p0;
            p0.u[0] = d0; p0.u[1] = d1; p0.u[2] = d2; p0.u[3] = d3;
            unsigned e0 = trunc_pk(ev[8], ev[9]),   e2 = trunc_pk(ev[12], ev[13]);
            unsigned e1 = trunc_pk(ev[10], ev[11]), e3 = trunc_pk(ev[14], ev[15]);
            permswap32(e0, e2);
            permswap32(e1, e3);
            union { bf16x8 v; unsigned u[4]; } p1;
            p1.u[0] = e0; p1.u[1] = e1; p1.u[2] = e2; p1.u[3] = e3;

            zacc = __builtin_amdgcn_mfma_f32_32x32x16_bf16(vf[tt * 2 + 0], p0.v, zacc, 0, 0, 0);
            zacc = __builtin_amdgcn_mfma_f32_32x32x16_bf16(vf[tt * 2 + 1], p1.v, zacc, 0, 0, 0);
        }
        __builtin_amdgcn_s_setprio(0);
    }

    float lf = (lacc[0] + lacc[1]) + (lacc[2] + lacc[3]);
    lf += __shfl_xor(lf, 32);
    const float rl = 1.f / lf;
    const int s = sblk + wv * 32 + l31;
    u16t* zrow = zT + ((long)b * 1024 + s) * 256 + h * 32;
#pragma unroll
    for (int g = 0; g < 4; g++) {
        const uint2 u = f2bf_pk4(zacc[g * 4 + 0] * rl, zacc[g * 4 + 1] * rl,
                                 zacc[g * 4 + 2] * rl, zacc[g * 4 + 3] * rl);
        *(uint2*)(zrow + g * 8 + hi * 4) = u;
    }
}

// ---------------------------------------------------------------------------
// Fused output GEMM (unchanged from R11): pure-DMA weight staging, 24 MFMAs.
// ---------------------------------------------------------------------------
__global__ __launch_bounds__(256) void out_gemm_kernel(
    const u16t* __restrict__ woF, const u16t* __restrict__ wrF,
    const u16t* __restrict__ zT, const u16t* __restrict__ xbT,
    const float* __restrict__ b_o, const float* __restrict__ b_res,
    float* __restrict__ out)
{
    __shared__ __align__(16) u16t Wo[16896];   // [64][264]
    __shared__ __align__(16) u16t Wr[8704];    // [64][136]

    const int lblk = blockIdx.x * 32, oblk = blockIdx.y, b = blockIdx.z;
    const int tid = threadIdx.x, lane = tid & 63, wv = tid >> 6;
    const int wm = wv >> 1, wn = wv & 1;
    const int l15 = lane & 15, quad = lane >> 4;
    const int ow = oblk * 64 + wm * 32;
    const int lw = lblk + wn * 16;

    // stage weights: pure DMA
    {
        const u16t* wo_src = woF + (long)oblk * 16896;
#pragma unroll
        for (int it = 0; it < 8; it++)
            async16(wo_src + it * 2048 + tid * 8, Wo + it * 2048 + tid * 8);
        if (tid < 64) async16(wo_src + 16384 + tid * 8, Wo + 16384 + tid * 8);
        const u16t* wr_src = wrF + (long)oblk * 8704;
#pragma unroll
        for (int it = 0; it < 4; it++)
            async16(wr_src + it * 2048 + tid * 8, Wr + it * 2048 + tid * 8);
        if (tid < 64) async16(wr_src + 8192 + tid * 8, Wr + 8192 + tid * 8);
    }

    // preload all 12 B fragments
    bf16x8 bfz[8], bfx[4];
    {
        const u16t* zrow = zT + ((long)b * 1024 + lw + l15) * 256 + quad * 8;
        const u16t* xrow = xbT + ((long)b * 1024 + lw + l15) * 128 + quad * 8;
#pragma unroll
        for (int ks = 0; ks < 8; ks++) bfz[ks] = *(const bf16x8*)(zrow + ks * 32);
#pragma unroll
        for (int ks = 0; ks < 4; ks++) bfx[ks] = *(const bf16x8*)(xrow + ks * 32);
    }
    __syncthreads();                           // drains DMA

    f32x4 acc0 = (f32x4)0.f, acc1 = (f32x4)0.f;

#pragma unroll
    for (int ks = 0; ks < 8; ks++) {
        const bf16x8 af0 = *(const bf16x8*)&Wo[(wm * 32 + l15) * 264 + ks * 32 + quad * 8];
        const bf16x8 af1 = *(const bf16x8*)&Wo[(wm * 32 + 16 + l15) * 264 + ks * 32 + quad * 8];
        acc0 = __builtin_amdgcn_mfma_f32_16x16x32_bf16(af0, bfz[ks], acc0, 0, 0, 0);
        acc1 = __builtin_amdgcn_mfma_f32_16x16x32_bf16(af1, bfz[ks], acc1, 0, 0, 0);
    }
#pragma unroll
    for (int ks = 0; ks < 4; ks++) {
        const bf16x8 af0 = *(const bf16x8*)&Wr[(wm * 32 + l15) * 136 + ks * 32 + quad * 8];
        const bf16x8 af1 = *(const bf16x8*)&Wr[(wm * 32 + 16 + l15) * 136 + ks * 32 + quad * 8];
        acc0 = __builtin_amdgcn_mfma_f32_16x16x32_bf16(af0, bfx[ks], acc0, 0, 0, 0);
        acc1 = __builtin_amdgcn_mfma_f32_16x16x32_bf16(af1, bfx[ks], acc1, 0, 0, 0);
    }

    const int lcol = lw + l15;
#pragma unroll
    for (int mi = 0; mi < 2; mi++) {
        const f32x4 a = (mi == 0) ? acc0 : acc1;
        const float4 bo = *(const float4*)(b_o + ow + mi * 16 + quad * 4);
        const float4 br = *(const float4*)(b_res + ow + mi * 16 + quad * 4);
        const float* bop = (const float*)&bo;
        const float* brp = (const float*)&br;
#pragma unroll
        for (int r = 0; r < 4; r++) {
            const int o = ow + mi * 16 + quad * 4 + r;
            out[((long)b * 128 + o) * 1024 + lcol] = a[r] + bop[r] + brp[r];
        }
    }
}

// ---------------------------------------------------------------------------
extern "C" void kernel_launch(void* const* d_in, const int* in_sizes, int n_in,
                              void* d_out, int out_size, void* d_ws, size_t ws_size,
                              hipStream_t stream)
{
    const float* x     = (const float*)d_in[0];
    const float* w_qkv = (const float*)d_in[1];
    const float* b_qkv = (const float*)d_in[2];
    const float* w_o   = (const float*)d_in[3];
    const float* b_o   = (const float*)d_in[4];
    const float* w_res = (const float*)d_in[5];
    const float* b_res = (const float*)d_in[6];
    float* out = (float*)d_out;

    u16t* xbT = (u16t*)d_ws;                   // [B][1024][128]
    u16t* qT  = xbT + (size_t)2097152;         // [B][H][1024][32]
    u16t* kF  = qT  + (size_t)4194304;         // [B*H][16 chunks][2048] (32x32 frag image)
    u16t* vF  = kF  + (size_t)4194304;         // [B*H][16 chunks][2048]
    u16t* zT  = vF  + (size_t)4194304;         // [B][1024][256]
    u16t* wqkvF = zT + (size_t)4194304;        // 8 x 14336
    u16t* woF   = wqkvF + (size_t)114688;      // 2 x 16896
    u16t* wrF   = woF + (size_t)33792;         // 2 x 8704

    pre_kernel<<<dim3(400), 256, 0, stream>>>(w_qkv, w_o, w_res, x, wqkvF, woF, wrF, xbT);
    qkv_gemm_kernel<<<dim3(8, 128), 256, 0, stream>>>(wqkvF, xbT, b_qkv, qT, kF, vF);
    attn_kernel13<<<dim3(128, 4), 512, 0, stream>>>(qT, kF, vF, zT);
    out_gemm_kernel<<<dim3(32, 2, 16), 256, 0, stream>>>(woF, wrF, zT, xbT, b_o, b_res, out);
}